// Round 1
// baseline (179.018 us; speedup 1.0000x reference)
//
#include <hip/hip_runtime.h>

// CTC forward loss (blank=0, reduction='mean', raw logits as log-probs).
// N=128 samples, T=1024 frames, V=1024 vocab, S_max=256 -> L=2S+1=513 states,
// but target_lengths <= 255 => end index <= 510, and alpha deps only flow
// upward in s, so states 0..511 suffice: one 512-thread block per sample.

constexpr int T_DIM = 1024;
constexpr int V_DIM = 1024;
constexpr int S_MAX = 256;
constexpr int L_ST  = 512;   // states computed per sample (s = threadIdx.x)

constexpr float INV_LN2 = 1.44269504088896340736f;
constexpr float LN2     = 0.69314718055994530942f;
constexpr float NEGB    = -1.442695e30f;  // -1e30 in base-2 domain

__device__ __forceinline__ float exp2_hw(float x) {
    float r; asm("v_exp_f32 %0, %1" : "=v"(r) : "v"(x)); return r;
}
__device__ __forceinline__ float log2_hw(float x) {
    float r; asm("v_log_f32 %0, %1" : "=v"(r) : "v"(x)); return r;
}

__launch_bounds__(512, 1)
__global__ void ctc_alpha_kernel(const float* __restrict__ logits,
                                 const int* __restrict__ targets,
                                 const int* __restrict__ tlen,
                                 float* __restrict__ losses) {
    // alpha double buffer with 2-slot NEG padding at the front:
    // state s lives at index s+2; indices 0,1 are permanent NEGB pads.
    __shared__ float bufA[L_ST + 2];
    __shared__ float bufB[L_ST + 2];

    const int n = blockIdx.x;
    const int s = threadIdx.x;            // 0..511
    const int odd = s & 1;

    // extended label: even s -> blank(0); odd s -> targets[n, (s-1)/2]
    int col = 0;
    int allow = 0;                        // skip-transition allowed (fixed per s)
    if (odd) {
        const int j = (s - 1) >> 1;
        col = targets[n * S_MAX + j];
        if (s >= 3) {
            const int pl = targets[n * S_MAX + j - 1];
            allow = (col != pl) ? 1 : 0;
        }
    }

    const float* gp = logits + (size_t)n * T_DIM * V_DIM + col;

    // alpha0 (base-2 domain): lp[0] at s=0,1 else NEG
    float aReg = NEGB;
    if (s < 2) aReg = gp[0] * INV_LN2;

    float* bc = bufA;   // current (read) buffer
    float* bn = bufB;   // next (write) buffer
    bufA[s + 2] = aReg;
    if (s < 2) { bufA[s] = NEGB; bufB[s] = NEGB; }   // permanent pads

    // lp prefetch pipeline, depth 4 (column fixed, stride = V floats per t)
    float l0 = gp[(size_t)1 * V_DIM];
    float l1 = gp[(size_t)2 * V_DIM];
    float l2 = gp[(size_t)3 * V_DIM];
    float l3 = gp[(size_t)4 * V_DIM];

    __syncthreads();

    #pragma unroll 4
    for (int t = 1; t < T_DIM; ++t) {
        const float lp = l0; l0 = l1; l1 = l2; l2 = l3;
        const int tp = t + 4;
        if (tp < T_DIM) l3 = gp[(size_t)tp * V_DIM];

        const float b  = bc[s + 1];              // alpha[s-1]
        const float c0 = bc[s];                  // alpha[s-2]
        const float c  = allow ? c0 : NEGB;
        const float a  = aReg;                   // alpha[s] (own, in register)

        const float m = fmaxf(fmaxf(a, b), c);
        const float r = m + log2_hw(exp2_hw(a - m) + exp2_hw(b - m) + exp2_hw(c - m));
        aReg = fmaf(lp, INV_LN2, r);

        bn[s + 2] = aReg;
        __syncthreads();
        float* tmp = bc; bc = bn; bn = tmp;
    }

    if (s == 0) {
        const int tl = tlen[n];
        const int e  = 2 * tl;                   // <= 510
        const float a1 = bc[e + 2];
        const float a0 = bc[e + 1];
        const float m  = fmaxf(a1, a0);
        const float ll = LN2 * (m + log2_hw(exp2_hw(a1 - m) + exp2_hw(a0 - m)));
        losses[n] = -ll / (float)tl;
    }
}

__global__ void reduce_mean_kernel(const float* __restrict__ losses,
                                   float* __restrict__ out, int N) {
    float v = 0.0f;
    for (int i = threadIdx.x; i < N; i += 64) v += losses[i];
    #pragma unroll
    for (int off = 32; off > 0; off >>= 1) v += __shfl_down(v, off);
    if (threadIdx.x == 0) out[0] = v / (float)N;
}

extern "C" void kernel_launch(void* const* d_in, const int* in_sizes, int n_in,
                              void* d_out, int out_size, void* d_ws, size_t ws_size,
                              hipStream_t stream) {
    const float* logits  = (const float*)d_in[0];
    const int*   targets = (const int*)d_in[1];
    // d_in[2] = input_lengths (all == T, unused)
    const int*   tlen    = (const int*)d_in[3];
    const int N = in_sizes[3];

    float* losses = (float*)d_ws;   // N floats of scratch

    ctc_alpha_kernel<<<N, L_ST, 0, stream>>>(logits, targets, tlen, losses);
    reduce_mean_kernel<<<1, 64, 0, stream>>>(losses, (float*)d_out, N);
}